// Round 6
// baseline (22.815 us; speedup 1.0000x reference)
//
#include <hip/hip_runtime.h>

#define NRAYS 16384
#define NB 129   // bin edges / samples per ray
#define NW 128   // weights / intervals per ray

// 2 rays per wave (32 lanes each), 4 waves per 256-thread block, zero
// __syncthreads. Each lane owns 4 intervals: float4 weight loads, 5-step
// segmented shuffle scan, inverted sampling (interval -> owned samples),
// and DIRECT register->global float4 stores for means/covs (no LDS
// transform). LDS only holds the per-ray nt scatter (4.2 KB/block).
__global__ __launch_bounds__(256) void mipnerf_2ray_kernel(
    const float* __restrict__ origins,     // [B,3]
    const float* __restrict__ directions,  // [B,3]
    const float* __restrict__ radii,       // [B,1]
    const float* __restrict__ t_vals,      // [B,129]
    const float* __restrict__ weights,     // [B,128]
    float* __restrict__ out_t,             // [B,129]
    float* __restrict__ out_means,         // [B,128,3]
    float* __restrict__ out_covs)          // [B,128,3]
{
    __shared__ __align__(16) float s_nt[4][2][132];   // [wave][half][sample], 528B rows

    const int tid  = threadIdx.x;
    const int wv   = tid >> 6;
    const int l    = tid & 63;
    const int half = l >> 5;                 // 0 = ray A, 1 = ray B
    const int l5   = l & 31;                 // lane within ray
    const int w    = (blockIdx.x << 2) + wv; // global wave id
    const int ray  = (w << 1) + half;

    // ---- inputs ----
    // weights: one float4 per lane (ray*512B + l5*16B -> 16B aligned)
    const float4 wf = *reinterpret_cast<const float4*>(weights + (long)ray * NW + 4 * l5);
    const float w0 = wf.x, w1 = wf.y, w2 = wf.z, w3 = wf.w;

    // bins b[0..4] = t_vals[ray][4*l5 .. 4*l5+4] (516B rows -> scalar loads)
    const float* trow = t_vals + (long)ray * NB;
    float b[5];
    #pragma unroll
    for (int j = 0; j < 5; ++j) b[j] = trow[4 * l5 + j];

    // per-ray uniforms (uniform within each 32-lane half)
    const float dx = directions[ray * 3 + 0];
    const float dy = directions[ray * 3 + 1];
    const float dz = directions[ray * 3 + 2];
    const float ox = origins[ray * 3 + 0];
    const float oy = origins[ray * 3 + 1];
    const float oz = origins[ray * 3 + 2];
    const float rad = radii[ray];

    // ---- max-blur + resample padding (segment-edge clamps) ----
    float wm1 = __shfl_up(w3, 1);   if (l5 == 0)  wm1 = w0;   // w[4l-1]
    float wp1 = __shfl_down(w0, 1); if (l5 == 31) wp1 = w3;   // w[4l+4]
    float wb[4];
    wb[0] = 0.5f * (fmaxf(wm1, w0) + fmaxf(w0, w1)) + 0.01f;
    wb[1] = 0.5f * (fmaxf(w0, w1) + fmaxf(w1, w2)) + 0.01f;
    wb[2] = 0.5f * (fmaxf(w1, w2) + fmaxf(w2, w3)) + 0.01f;
    wb[3] = 0.5f * (fmaxf(w2, w3) + fmaxf(w3, wp1)) + 0.01f;

    // ---- segmented (32-lane) inclusive scan of per-lane quad sums ----
    float S = (wb[0] + wb[1]) + (wb[2] + wb[3]);
    #pragma unroll
    for (int off = 1; off < 32; off <<= 1) {
        const float t = __shfl_up(S, off);     // crosses half boundary but masked below
        if (l5 >= off) S += t;
    }
    const float inv_wsum = 1.0f / __shfl(S, (l & 32) | 31);   // segment's lane 31
    // eps-pad branch of reference is identically 0: every wb >= 0.01 -> wsum >= 1.28

    // prefix points around this lane's 4 intervals
    const float P4 = S;
    const float P3 = P4 - wb[3];
    const float P2 = P3 - wb[2];
    const float P1 = P2 - wb[1];
    const float P0 = P1 - wb[0];
    float c[5];
    c[0] = (l5 == 0)  ? 0.0f : fminf(1.0f, P0 * inv_wsum);
    c[1] = fminf(1.0f, P1 * inv_wsum);
    c[2] = fminf(1.0f, P2 * inv_wsum);
    c[3] = fminf(1.0f, P3 * inv_wsum);
    c[4] = (l5 == 31) ? 1.0f : fminf(1.0f, P4 * inv_wsum);

    // ---- inverted sampling: interval j owns s in [ceil(c[j]/step), ceil(c[j+1]/step)) ----
    const float ueps     = 1.0f - 1.1920929e-7f;
    const float step     = ueps / 128.0f;        // exact (power-of-2 divide)
    const float inv_step = 128.0f / ueps;
    int sidx[5];
    #pragma unroll
    for (int j = 0; j < 5; ++j) sidx[j] = (int)ceilf(c[j] * inv_step);
    // l5==31: c[4]=1 -> ceil(128.000015) = 129 covers s=128 (u=128*step==ueps exactly)

    float* ntrow = s_nt[wv][half];
    #pragma unroll
    for (int j = 0; j < 4; ++j) {
        const float inv_d = 1.0f / (c[j + 1] - c[j]);   // loop empty whenever denom == 0
        const float db = b[j + 1] - b[j];
        for (int s = sidx[j]; s < sidx[j + 1]; ++s) {
            float tt = ((float)s * step - c[j]) * inv_d;
            tt = fminf(fmaxf(tt, 0.0f), 1.0f);
            ntrow[s] = fmaf(tt, db, b[j]);
        }
    }
    __builtin_amdgcn_wave_barrier();   // order scatter before re-read (same wave, DS in-order)

    // ---- read back nt[4l5 .. 4l5+4] (aligned float4 + 1 scalar) ----
    const float4 n4 = *reinterpret_cast<const float4*>(ntrow + 4 * l5);
    const float nt[5] = { n4.x, n4.y, n4.z, n4.w, ntrow[4 * l5 + 4] };

    // ---- conical frustum -> Gaussian, 4 intervals/lane, direct f4 stores ----
    const float rad2 = rad * rad;
    const float dx2 = dx * dx, dy2 = dy * dy, dz2 = dz * dz;
    const float inv_dms = 1.0f / (dx2 + dy2 + dz2 + 1e-10f);
    const float nullx = 1.0f - dx2 * inv_dms;
    const float nully = 1.0f - dy2 * inv_dms;
    const float nullz = 1.0f - dz2 * inv_dms;

    float m[12], cv[12];
    #pragma unroll
    for (int k = 0; k < 4; ++k) {
        const float mu = 0.5f * (nt[k] + nt[k + 1]);
        const float hw = 0.5f * (nt[k + 1] - nt[k]);
        const float mu2 = mu * mu, hw2 = hw * hw;
        const float inv_denom = 1.0f / (3.0f * mu2 + hw2);
        const float t_mean = mu + 2.0f * mu * hw2 * inv_denom;
        const float t_var  = hw2 * (1.0f / 3.0f)
                           - (4.0f / 15.0f) * (hw2 * hw2 * (12.0f * mu2 - hw2) * inv_denom * inv_denom);
        const float r_var  = rad2 * (0.25f * mu2 + (5.0f / 12.0f) * hw2
                                     - (4.0f / 15.0f) * hw2 * hw2 * inv_denom);
        m[3 * k + 0]  = fmaf(dx, t_mean, ox);
        m[3 * k + 1]  = fmaf(dy, t_mean, oy);
        m[3 * k + 2]  = fmaf(dz, t_mean, oz);
        cv[3 * k + 0] = fmaf(t_var, dx2, r_var * nullx);
        cv[3 * k + 1] = fmaf(t_var, dy2, r_var * nully);
        cv[3 * k + 2] = fmaf(t_var, dz2, r_var * nullz);
    }

    float4* pm = reinterpret_cast<float4*>(out_means + (long)ray * (NW * 3)) + 3 * l5;
    float4* pc = reinterpret_cast<float4*>(out_covs  + (long)ray * (NW * 3)) + 3 * l5;
    pm[0] = make_float4(m[0], m[1], m[2],  m[3]);
    pm[1] = make_float4(m[4], m[5], m[6],  m[7]);
    pm[2] = make_float4(m[8], m[9], m[10], m[11]);
    pc[0] = make_float4(cv[0], cv[1], cv[2],  cv[3]);
    pc[1] = make_float4(cv[4], cv[5], cv[6],  cv[7]);
    pc[2] = make_float4(cv[8], cv[9], cv[10], cv[11]);

    // ---- out_t writeout (contiguous 4B stores, 256B per instruction) ----
    float* po = out_t + (long)ray * NB;
    #pragma unroll
    for (int k = 0; k < 4; ++k) po[l5 + 32 * k] = ntrow[l5 + 32 * k];
    if (l5 == 0) po[128] = ntrow[128];
}

extern "C" void kernel_launch(void* const* d_in, const int* in_sizes, int n_in,
                              void* d_out, int out_size, void* d_ws, size_t ws_size,
                              hipStream_t stream) {
    const float* origins    = (const float*)d_in[0];
    const float* directions = (const float*)d_in[1];
    const float* radii      = (const float*)d_in[2];
    const float* t_vals     = (const float*)d_in[3];
    const float* weights    = (const float*)d_in[4];

    float* out_t     = (float*)d_out;
    float* out_means = out_t + (long)NRAYS * NB;
    float* out_covs  = out_means + (long)NRAYS * NW * 3;

    const int grid = NRAYS / 8;   // 2048 blocks x 256 threads (2 rays per wave)
    mipnerf_2ray_kernel<<<grid, 256, 0, stream>>>(
        origins, directions, radii, t_vals, weights, out_t, out_means, out_covs);
}

// Round 8
// 18.429 us; speedup vs baseline: 1.2380x; 1.2380x over previous
//
#include <hip/hip_runtime.h>

#define NRAYS 16384
#define NB 129   // bin edges / samples per ray
#define NW 128   // weights / intervals per ray

typedef float f32x4 __attribute__((ext_vector_type(4)));   // native vector: valid for nontemporal builtins

// R4 structure (best: 19.28us) + non-temporal output stores.
// One wave per ray, 4 waves per 256-thread block, zero __syncthreads.
// Outputs are write-once streams ~2x aggregate L2 -> bypass L2 with nt stores.
__global__ __launch_bounds__(256) void mipnerf_nt_kernel(
    const float* __restrict__ origins,     // [B,3]
    const float* __restrict__ directions,  // [B,3]
    const float* __restrict__ radii,       // [B,1]
    const float* __restrict__ t_vals,      // [B,129]
    const float* __restrict__ weights,     // [B,128]
    float* __restrict__ out_t,             // [B,129]
    float* __restrict__ out_means,         // [B,128,3]
    float* __restrict__ out_covs)          // [B,128,3]
{
    __shared__ __align__(16) float s_nt  [4][NB + 3];   // 132 floats/row, 16B-aligned rows
    __shared__ __align__(16) float s_mean[4][NW * 3];   // 1536B rows
    __shared__ __align__(16) float s_cov [4][NW * 3];

    const int tid = threadIdx.x;
    const int wv  = tid >> 6;      // wave = ray slot
    const int l   = tid & 63;
    const int ray = (blockIdx.x << 2) + wv;

    // ---- direct register loads (no staging) ----
    const float2 wp = *reinterpret_cast<const float2*>(weights + (long)ray * NW + 2 * l);
    const float w0 = wp.x, w1 = wp.y;              // w[2l], w[2l+1]
    const float* trow = t_vals + (long)ray * NB;
    const float b0 = trow[2 * l];                  // neighbor-only bin access (L1 reuse)
    const float b1 = trow[2 * l + 1];
    const float b2 = trow[2 * l + 2];

    // per-ray scalars (uniform per wave -> broadcast loads)
    const float dx = directions[ray * 3 + 0];
    const float dy = directions[ray * 3 + 1];
    const float dz = directions[ray * 3 + 2];
    const float ox = origins[ray * 3 + 0];
    const float oy = origins[ray * 3 + 1];
    const float oz = origins[ray * 3 + 2];
    const float rad = radii[ray];

    // ---- max-blur + resample padding (neighbors via shuffle) ----
    float wm1 = __shfl_up(w1, 1);   if (l == 0)  wm1 = w0;   // w[2l-1]
    float wp1 = __shfl_down(w0, 1); if (l == 63) wp1 = w1;   // w[2l+2]
    const float mx01 = fmaxf(w0, w1);
    const float wb0 = 0.5f * (fmaxf(wm1, w0) + mx01) + 0.01f;
    const float wb1 = 0.5f * (mx01 + fmaxf(w1, wp1)) + 0.01f;

    // ---- wave-wide inclusive scan of pair sums (6 shuffle steps) ----
    float S = wb0 + wb1;
    #pragma unroll
    for (int off = 1; off < 64; off <<= 1) {
        const float t = __shfl_up(S, off);
        if (l >= off) S += t;
    }
    const float W1 = S;          // prefix through w[2l+1]
    const float W0 = S - wb1;    // prefix through w[2l]
    const float inv_wsum = 1.0f / __shfl(S, 63);
    // eps-pad branch of reference is identically 0: every wb >= 0.01 -> wsum >= 1.28

    // lane-resident cdf values bounding intervals 2l and 2l+1
    const float c_lo  = (l == 0)  ? 0.0f : fminf(1.0f, (W0 - wb0) * inv_wsum);
    const float c_mid = fminf(1.0f, W0 * inv_wsum);
    const float c_hi  = (l == 63) ? 1.0f : fminf(1.0f, W1 * inv_wsum);

    // ---- inverted sampling: interval k owns s in [ceil(cdf[k]/step), ceil(cdf[k+1]/step)) ----
    const float ueps     = 1.0f - 1.1920929e-7f;
    const float step     = ueps / 128.0f;
    const float inv_step = 128.0f / ueps;
    const int s0 = (int)ceilf(c_lo  * inv_step);
    const int s1 = (int)ceilf(c_mid * inv_step);
    const int s2 = (int)ceilf(c_hi  * inv_step);   // c_hi=1 -> 129, covers s=128

    float* ntrow = s_nt[wv];
    {
        const float inv_d = 1.0f / (c_mid - c_lo);
        const float db = b1 - b0;
        for (int s = s0; s < s1; ++s) {
            float tt = ((float)s * step - c_lo) * inv_d;
            tt = fminf(fmaxf(tt, 0.0f), 1.0f);
            ntrow[s] = fmaf(tt, db, b0);
        }
    }
    {
        const float inv_d = 1.0f / (c_hi - c_mid);
        const float db = b2 - b1;
        for (int s = s1; s < s2; ++s) {
            float tt = ((float)s * step - c_mid) * inv_d;
            tt = fminf(fmaxf(tt, 0.0f), 1.0f);
            ntrow[s] = fmaf(tt, db, b1);
        }
    }
    __builtin_amdgcn_wave_barrier();   // order scatter before neighbor reads (same wave)

    const float n0 = ntrow[2 * l];
    const float n1 = ntrow[2 * l + 1];
    const float n2 = ntrow[2 * l + 2];

    const float rad2 = rad * rad;
    const float dx2 = dx * dx, dy2 = dy * dy, dz2 = dz * dz;
    const float inv_dms = 1.0f / (dx2 + dy2 + dz2 + 1e-10f);
    const float nullx = 1.0f - dx2 * inv_dms;
    const float nully = 1.0f - dy2 * inv_dms;
    const float nullz = 1.0f - dz2 * inv_dms;

    // ---- conical frustum -> Gaussian for intervals 2l, 2l+1 ----
    float* mrow = s_mean[wv] + 6 * l;
    float* crow = s_cov[wv]  + 6 * l;
    const float tt0[2] = { n0, n1 };
    const float tt1[2] = { n1, n2 };
    #pragma unroll
    for (int k = 0; k < 2; ++k) {
        const float mu = 0.5f * (tt0[k] + tt1[k]);
        const float hw = 0.5f * (tt1[k] - tt0[k]);
        const float mu2 = mu * mu, hw2 = hw * hw;
        const float inv_denom = 1.0f / (3.0f * mu2 + hw2);
        const float t_mean = mu + 2.0f * mu * hw2 * inv_denom;
        const float t_var  = hw2 * (1.0f / 3.0f)
                           - (4.0f / 15.0f) * (hw2 * hw2 * (12.0f * mu2 - hw2) * inv_denom * inv_denom);
        const float r_var  = rad2 * (0.25f * mu2 + (5.0f / 12.0f) * hw2
                                     - (4.0f / 15.0f) * hw2 * hw2 * inv_denom);
        mrow[3 * k + 0] = fmaf(dx, t_mean, ox);
        mrow[3 * k + 1] = fmaf(dy, t_mean, oy);
        mrow[3 * k + 2] = fmaf(dz, t_mean, oz);
        crow[3 * k + 0] = fmaf(t_var, dx2, r_var * nullx);
        crow[3 * k + 1] = fmaf(t_var, dy2, r_var * nully);
        crow[3 * k + 2] = fmaf(t_var, dz2, r_var * nullz);
    }
    __builtin_amdgcn_wave_barrier();   // order mean/cov writes before float4 re-read (same wave)

    // ---- per-wave coalesced NON-TEMPORAL writeout (bypass L2 for write-once streams) ----
    float* po = out_t + (long)ray * NB;
    __builtin_nontemporal_store(ntrow[l],      po + l);
    __builtin_nontemporal_store(ntrow[64 + l], po + 64 + l);
    if (l == 0) __builtin_nontemporal_store(ntrow[128], po + 128);

    f32x4* pm = reinterpret_cast<f32x4*>(out_means + (long)ray * (NW * 3));  // 16B-aligned rows
    f32x4* pc = reinterpret_cast<f32x4*>(out_covs  + (long)ray * (NW * 3));
    const f32x4* sm = reinterpret_cast<const f32x4*>(s_mean[wv]);
    const f32x4* sc = reinterpret_cast<const f32x4*>(s_cov[wv]);
    __builtin_nontemporal_store(sm[l], pm + l);
    __builtin_nontemporal_store(sc[l], pc + l);
    if (l < 32) {
        __builtin_nontemporal_store(sm[64 + l], pm + 64 + l);
        __builtin_nontemporal_store(sc[64 + l], pc + 64 + l);
    }
}

extern "C" void kernel_launch(void* const* d_in, const int* in_sizes, int n_in,
                              void* d_out, int out_size, void* d_ws, size_t ws_size,
                              hipStream_t stream) {
    const float* origins    = (const float*)d_in[0];
    const float* directions = (const float*)d_in[1];
    const float* radii      = (const float*)d_in[2];
    const float* t_vals     = (const float*)d_in[3];
    const float* weights    = (const float*)d_in[4];

    float* out_t     = (float*)d_out;
    float* out_means = out_t + (long)NRAYS * NB;
    float* out_covs  = out_means + (long)NRAYS * NW * 3;

    const int grid = NRAYS / 4;   // 4096 blocks x 256 threads, 1 wave per ray
    mipnerf_nt_kernel<<<grid, 256, 0, stream>>>(
        origins, directions, radii, t_vals, weights, out_t, out_means, out_covs);
}